// Round 9
// baseline (369.256 us; speedup 1.0000x reference)
//
#include <hip/hip_runtime.h>

typedef _Float16 f16;
typedef _Float16 f16x8 __attribute__((ext_vector_type(8)));
typedef float f32x4 __attribute__((ext_vector_type(4)));

// ---- workspace layout (bytes) ----
#define WS_EWIH 4194304                // enc Wih f16 [384][32] (k>=29 zero)
#define WS_EWHH 4218880                // enc Whh f16 [384][128]
#define WS_DWC  4317184                // dec combined f16 [512][128]
#define WS_DWHH 4448256                // dec Whh f16 [384][128]
#define WS_BIAS 4546560                // f32[1024]
#define WS_W1F  4550656                // conv1 B-frags f16 [9][16][32]
#define WS_W2F  4559872                // conv2 B-frags f16 [2][32][32]
#define WS_FCWF 4563968                // fc weights f16 [128][128]

static __device__ __forceinline__ f32x4 mfma16(f16x8 a, f16x8 b, f32x4 c) {
    return __builtin_amdgcn_mfma_f32_16x16x32_f16(a, b, c, 0, 0, 0);
}
static __device__ __forceinline__ float fexp2n(float x) {   // 2^(-x*log2e)
    return __builtin_amdgcn_exp2f(x * -1.4426950408889634f);
}

// ---------------- prep: f32 -> f16 packs ----------------
__global__ void k_prep(const float* __restrict__ eWih, const float* __restrict__ eWhh,
                       const float* __restrict__ ebih, const float* __restrict__ ebhh,
                       const float* __restrict__ dWih, const float* __restrict__ dWhh,
                       const float* __restrict__ dbih, const float* __restrict__ dbhh,
                       const float* __restrict__ w1, const float* __restrict__ w2,
                       const float* __restrict__ fcw,
                       char* __restrict__ ws)
{
    f16* ewih = (f16*)(ws + WS_EWIH);
    f16* ewhh = (f16*)(ws + WS_EWHH);
    f16* dwc  = (f16*)(ws + WS_DWC);
    f16* dwhh = (f16*)(ws + WS_DWHH);
    float* bias = (float*)(ws + WS_BIAS);
    f16* w1f = (f16*)(ws + WS_W1F);
    f16* w2f = (f16*)(ws + WS_W2F);
    f16* fcwf = (f16*)(ws + WS_FCWF);
    const int total = 12288 + 49152 + 65536 + 49152 + 1024 + 4608 + 2048 + 16384;
    for (int i = blockIdx.x * 256 + threadIdx.x; i < total; i += gridDim.x * 256) {
        int j = i;
        if (j < 12288) { int g = j >> 5, k = j & 31;
            ewih[j] = (f16)((k < 29) ? eWih[g * 29 + k] : 0.0f); continue; }
        j -= 12288;
        if (j < 49152) { ewhh[j] = (f16)eWhh[j]; continue; }
        j -= 49152;
        if (j < 65536) { int row = j >> 7, k = j & 127; float v;
            if (row < 256)      v = dWih[row * 128 + k] + dWhh[row * 128 + k];
            else if (row < 384) v = dWih[row * 128 + k];
            else                v = dWhh[(row - 128) * 128 + k];
            dwc[j] = (f16)v; continue; }
        j -= 65536;
        if (j < 49152) { dwhh[j] = (f16)dWhh[j]; continue; }
        j -= 49152;
        if (j < 1024) {
            if (j < 256)        bias[j] = ebih[j] + ebhh[j];
            else if (j < 384)   bias[j] = ebih[j];
            else if (j < 512)   bias[j] = ebhh[j - 128];
            else if (j < 768)   bias[j] = dbih[j - 512] + dbhh[j - 512];
            else if (j < 896)   bias[j] = dbih[j - 512];
            else                bias[j] = dbhh[j - 640];
            continue; }
        j -= 1024;
        if (j < 4608) {   // w1f[kk][co][k]: w1 (16,27,3,3) OIHW; k>=27 -> 0
            int kk = j >> 9, rem = j & 511, co = rem >> 5, k = rem & 31;
            w1f[j] = (f16)((k < 27) ? w1[co * 243 + k * 9 + kk] : 0.0f); continue; }
        j -= 4608;
        if (j < 2048) {   // w2f[s][co][k]
            int s = j >> 10, rem = j & 1023, co = rem >> 5, k = rem & 31;
            int kk2 = 2 * s + (k >= 16), ci = k & 15;
            w2f[j] = (f16)w2[co * 64 + ci * 4 + kk2]; continue; }
        j -= 2048;
        fcwf[j] = (f16)fcw[j];
    }
}

// ---------------- fused CNN + GRU + heads: 512 threads, 16 rows/block ----------------
// KEY CHANGE vs r8: all loop-invariant GRU weights go global -> LDS staging chunk ->
// registers BEFORE the step loops, under __launch_bounds__(512,2) (256-VGPR budget).
// LLVM cannot rematerialize LDS reads across barriers where the staging buffer is
// overwritten, so the frags stay register-resident -- killing the 256 KB/step/CU of
// remat'd L1/L2 weight traffic that was the measured ~4300 cyc/step wall (r3-r8).
// z_cnn is carried in 4 registers/thread so the staging region aliases pn_s.
__global__ __launch_bounds__(512, 2) void k_gru(
    const float* __restrict__ cin,
    const float* __restrict__ lin,
    const float* __restrict__ b1, const float* __restrict__ b2,
    const float* __restrict__ fcb,
    const char* __restrict__ ws,
    const float* __restrict__ dis_w, const float* __restrict__ dis_b,
    const float* __restrict__ value_w, const float* __restrict__ value_b,
    float* __restrict__ out)
{
    __shared__ __align__(16) char smem[47360];
    // [0,8192)      h bufs (2 x 4096, XOR swizzle);  CNN alias: a1f [0,6912)
    // [8192,10240)  x_s double buffer
    // [10240,43008) wstage 32 KB  (aliases pn_s 16x264 f32 = 16896 B, used at heads)
    // [43008,47360) vf
    f16 (*a1f)[9][24]  = (f16(*)[9][24])(smem);
    f16 (*x_s)[16][32] = (f16(*)[16][32])(smem + 8192);
    char* wstage       = smem + 10240;
    float (*pn_s)[264] = (float(*)[264])(smem + 10240);
    f16 (*vf)[136]     = (f16(*)[136])(smem + 43008);
#define HS(B) (smem + (B) * 4096)

    const int tid = threadIdx.x;
    const int wv = tid >> 6;
    const int lane = tid & 63;
    const int nl = lane & 15;
    const int quad = lane >> 4;
    const int j0 = wv * 16;
    const int row0 = blockIdx.x * 16;

    const f16* ewih = (const f16*)(ws + WS_EWIH);
    const f16* ewhh = (const f16*)(ws + WS_EWHH);
    const f16* dwc  = (const f16*)(ws + WS_DWC);
    const f16* dwhh = (const f16*)(ws + WS_DWHH);
    const float* bias = (const float*)(ws + WS_BIAS);
    const f16* w1f = (const f16*)(ws + WS_W1F);
    const f16* w2f = (const f16*)(ws + WS_W2F);
    const f16* fcwf = (const f16*)(ws + WS_FCWF);

    float zc[4];   // z_cnn slice, register-resident until heads

    // ================= CNN prologue (16 images = this block's rows) =================
    {
        const float* imgp = cin + (size_t)(row0 + nl) * 1728 + quad * 8;
        float b1v = b1[nl];
        for (int p = wv; p < 9; p += 8) {
            int oy = p / 3, ox = p % 3;
            f32x4 acc = {b1v, b1v, b1v, b1v};
            #pragma unroll
            for (int kk = 0; kk < 9; kk++) {
                f16x8 bw = *(const f16x8*)(w1f + (kk * 16 + nl) * 32 + quad * 8);
                int pix = (2 * oy + kk / 3) * 8 + (2 * ox + kk % 3);
                const float* s = imgp + pix * 27;
                f16x8 a;
                #pragma unroll
                for (int jj = 0; jj < 8; jj++) a[jj] = (f16)s[jj];
                acc = mfma16(a, bw, acc);
            }
            #pragma unroll
            for (int r = 0; r < 4; r++)
                a1f[quad * 4 + r][p][nl] = (f16)fmaxf(acc[r], 0.0f);
        }
        __syncthreads();
        {
            int pos = wv >> 1, nt = wv & 1;
            int y = pos >> 1, x = pos & 1;
            float bv = b2[nt * 16 + nl];
            f32x4 acc = {bv, bv, bv, bv};
            #pragma unroll
            for (int s = 0; s < 2; s++) {
                int kk2 = 2 * s + (quad >> 1);
                int pos1 = (y + (kk2 >> 1)) * 3 + (x + (kk2 & 1));
                f16x8 a = *(const f16x8*)(&a1f[nl][pos1][(quad & 1) * 8]);
                f16x8 b = *(const f16x8*)(w2f + ((size_t)s * 32 + nt * 16 + nl) * 32 + quad * 8);
                acc = mfma16(a, b, acc);
            }
            #pragma unroll
            for (int r = 0; r < 4; r++)
                vf[quad * 4 + r][(nt * 16 + nl) * 4 + (y * 2 + x)] = (f16)fmaxf(acc[r], 0.0f);
        }
        __syncthreads();
        {
            int o = wv * 16 + nl;
            float bv = fcb[o];
            f32x4 acc = {bv, bv, bv, bv};
            #pragma unroll
            for (int kt = 0; kt < 4; kt++) {
                f16x8 a = *(const f16x8*)(&vf[nl][kt * 32 + quad * 8]);
                f16x8 b = *(const f16x8*)(fcwf + o * 128 + kt * 32 + quad * 8);
                acc = mfma16(a, b, acc);
            }
            #pragma unroll
            for (int r = 0; r < 4; r++)
                zc[r] = fmaxf(acc[r], 0.0f);
        }
        __syncthreads();   // a1f dead; safe to zero h bufs below
    }

    for (int i = tid; i < 4096; i += 512) ((f16*)smem)[i] = (f16)0.0f;

    // LDS address constants (XOR swizzle)
    const int lane7 = nl & 7;
    int rb[4], wb[4];
    #pragma unroll
    for (int kt = 0; kt < 4; kt++)
        rb[kt] = nl * 256 + (((4 * kt + quad) ^ lane7) << 4);
    #pragma unroll
    for (int r = 0; r < 4; r++) {
        int row = quad * 4 + r;
        wb[r] = row * 256 + ((((2 * wv + (nl >> 3)) ^ (row & 7)) << 3) + lane7) * 2;
    }

    // frag byte offset inside a 128x128 f16 staged gate chunk
    const int frag_off0 = ((j0 + nl) * 128) * 2 + (quad * 8) * 2;

    float ho[4];
    #pragma unroll
    for (int r = 0; r < 4; r++) ho[r] = 0.0f;

    const int xr = tid >> 5, xc = tid & 31;   // x staging: 16 rows x 32 cols
    const bool xok = (xc < 29);
    const size_t lin_base = (size_t)(row0 + xr) * 1856 + xc;

    // ================= encoder =================
    {
        float eb_r, eb_z, eb_xn, eb_hn;
        { int c = j0 + nl;
          eb_r = bias[c]; eb_z = bias[128 + c]; eb_xn = bias[256 + c]; eb_hn = bias[384 + c]; }

        // ---- stage weights into LDS, read frags into registers (un-remat-able) ----
        f16x8 we_r[4], we_z[4], we_hn[4], we_xr, we_xz, we_xn;
        {
            // ewih: 384x32 f16 = 24576 B
            __syncthreads();
            for (int i = tid * 16; i < 24576; i += 512 * 16)
                *(f16x8*)(wstage + i) = *(const f16x8*)((const char*)ewih + i);
            __syncthreads();
            we_xr = *(const f16x8*)(wstage + ((j0 + nl) * 32 + quad * 8) * 2);
            we_xz = *(const f16x8*)(wstage + ((128 + j0 + nl) * 32 + quad * 8) * 2);
            we_xn = *(const f16x8*)(wstage + ((256 + j0 + nl) * 32 + quad * 8) * 2);
            // ewhh: 3 gate chunks of 128x128 f16 = 32768 B
            #pragma unroll
            for (int g = 0; g < 3; g++) {
                __syncthreads();
                const char* src = (const char*)(ewhh + g * 128 * 128);
                for (int i = tid * 16; i < 32768; i += 512 * 16)
                    *(f16x8*)(wstage + i) = *(const f16x8*)(src + i);
                __syncthreads();
                #pragma unroll
                for (int kt = 0; kt < 4; kt++) {
                    f16x8 v = *(const f16x8*)(wstage + frag_off0 + kt * 64);
                    if (g == 0) we_r[kt] = v;
                    else if (g == 1) we_z[kt] = v;
                    else we_hn[kt] = v;
                }
            }
            __syncthreads();
        }

        float xv = xok ? lin[lin_base] : 0.0f;

#define ENC_STEP(BUF, OBUF, TN)                                                      \
        do {                                                                         \
            x_s[BUF][xr][xc] = (f16)xv;                                              \
            __syncthreads();                                                         \
            f16x8 ax = *(const f16x8*)(&x_s[BUF][nl][quad * 8]);                     \
            f16x8 ah0 = *(const f16x8*)(HS(BUF) + rb[0]);                            \
            f16x8 ah1 = *(const f16x8*)(HS(BUF) + rb[1]);                            \
            f16x8 ah2 = *(const f16x8*)(HS(BUF) + rb[2]);                            \
            f16x8 ah3 = *(const f16x8*)(HS(BUF) + rb[3]);                            \
            if ((TN) < 64) xv = xok ? lin[lin_base + (TN) * 29] : 0.0f;              \
            f32x4 aR  = {eb_r, eb_r, eb_r, eb_r};                                    \
            f32x4 aZ  = {eb_z, eb_z, eb_z, eb_z};                                    \
            f32x4 aXN = {eb_xn, eb_xn, eb_xn, eb_xn};                                \
            f32x4 aHN = {eb_hn, eb_hn, eb_hn, eb_hn};                                \
            aR  = mfma16(ax, we_xr, aR);                                             \
            aZ  = mfma16(ax, we_xz, aZ);                                             \
            aXN = mfma16(ax, we_xn, aXN);                                            \
            aR  = mfma16(ah0, we_r[0], aR);  aR  = mfma16(ah1, we_r[1], aR);         \
            aR  = mfma16(ah2, we_r[2], aR);  aR  = mfma16(ah3, we_r[3], aR);         \
            aZ  = mfma16(ah0, we_z[0], aZ);  aZ  = mfma16(ah1, we_z[1], aZ);         \
            aZ  = mfma16(ah2, we_z[2], aZ);  aZ  = mfma16(ah3, we_z[3], aZ);         \
            aHN = mfma16(ah0, we_hn[0], aHN); aHN = mfma16(ah1, we_hn[1], aHN);      \
            aHN = mfma16(ah2, we_hn[2], aHN); aHN = mfma16(ah3, we_hn[3], aHN);      \
            _Pragma("unroll")                                                        \
            for (int r = 0; r < 4; r++) {                                            \
                float ea = fexp2n(aR[r]), eb = fexp2n(aZ[r]);                        \
                float s1 = 1.0f + ea, s2 = 1.0f + eb;                                \
                float R = __builtin_amdgcn_rcpf(s1 * s2);                            \
                float rg = s2 * R, zg = s1 * R;                                      \
                float ec = fexp2n(2.0f * (aXN[r] + rg * aHN[r]));                    \
                float ng = (1.0f - ec) * __builtin_amdgcn_rcpf(1.0f + ec);           \
                float h = ng + zg * (ho[r] - ng);                                    \
                ho[r] = h;                                                           \
                *(f16*)(HS(OBUF) + wb[r]) = (f16)h;                                  \
            }                                                                        \
        } while (0)

        for (int t = 0; t < 64; t += 2) {
            ENC_STEP(0, 1, t + 1);
            ENC_STEP(1, 0, t + 2);
        }
#undef ENC_STEP
    }

    // ================= decoder =================
    float db_r, db_z, db_xn, db_hn;
    { int c = j0 + nl;
      db_r = bias[512 + c]; db_z = bias[640 + c]; db_xn = bias[768 + c]; db_hn = bias[896 + c]; }

    // step 0: xin = 0 -> gx = bih; Whh-only frags direct from global (used once)
    {
        __syncthreads();
        f16x8 ah0 = *(const f16x8*)(HS(0) + rb[0]);
        f16x8 ah1 = *(const f16x8*)(HS(0) + rb[1]);
        f16x8 ah2 = *(const f16x8*)(HS(0) + rb[2]);
        f16x8 ah3 = *(const f16x8*)(HS(0) + rb[3]);
        int gr = j0 + nl;
        f32x4 aR  = {db_r, db_r, db_r, db_r};
        f32x4 aZ  = {db_z, db_z, db_z, db_z};
        f32x4 aHN = {db_hn, db_hn, db_hn, db_hn};
        #pragma unroll
        for (int kt = 0; kt < 4; kt++) {
            f16x8 b0 = *(const f16x8*)(dwhh + gr * 128 + kt * 32 + quad * 8);
            f16x8 b1 = *(const f16x8*)(dwhh + (128 + gr) * 128 + kt * 32 + quad * 8);
            f16x8 b2 = *(const f16x8*)(dwhh + (256 + gr) * 128 + kt * 32 + quad * 8);
            f16x8 a = (kt == 0) ? ah0 : (kt == 1) ? ah1 : (kt == 2) ? ah2 : ah3;
            aR  = mfma16(a, b0, aR);
            aZ  = mfma16(a, b1, aZ);
            aHN = mfma16(a, b2, aHN);
        }
        #pragma unroll
        for (int r = 0; r < 4; r++) {
            float ea = fexp2n(aR[r]), eb = fexp2n(aZ[r]);
            float s1 = 1.0f + ea, s2 = 1.0f + eb;
            float R = __builtin_amdgcn_rcpf(s1 * s2);
            float rg = s2 * R, zg = s1 * R;
            float ec = fexp2n(2.0f * (db_xn + rg * aHN[r]));
            float ng = (1.0f - ec) * __builtin_amdgcn_rcpf(1.0f + ec);
            float h = ng + zg * (ho[r] - ng);
            ho[r] = h;
            *(f16*)(HS(1) + wb[r]) = (f16)h;
        }
    }
    // steps 1..63: xin == h -> combined weights (LDS-staged -> registers)
    {
        f16x8 wd_r[4], wd_z[4], wd_xn[4], wd_hn[4];
        #pragma unroll
        for (int g = 0; g < 4; g++) {
            __syncthreads();
            const char* src = (const char*)(dwc + g * 128 * 128);
            for (int i = tid * 16; i < 32768; i += 512 * 16)
                *(f16x8*)(wstage + i) = *(const f16x8*)(src + i);
            __syncthreads();
            #pragma unroll
            for (int kt = 0; kt < 4; kt++) {
                f16x8 v = *(const f16x8*)(wstage + frag_off0 + kt * 64);
                if (g == 0) wd_r[kt] = v;
                else if (g == 1) wd_z[kt] = v;
                else if (g == 2) wd_xn[kt] = v;
                else wd_hn[kt] = v;
            }
        }

#define DEC_STEP(BUF, OBUF)                                                          \
        do {                                                                         \
            __syncthreads();                                                         \
            f16x8 ah0 = *(const f16x8*)(HS(BUF) + rb[0]);                            \
            f16x8 ah1 = *(const f16x8*)(HS(BUF) + rb[1]);                            \
            f16x8 ah2 = *(const f16x8*)(HS(BUF) + rb[2]);                            \
            f16x8 ah3 = *(const f16x8*)(HS(BUF) + rb[3]);                            \
            f32x4 aR  = {db_r, db_r, db_r, db_r};                                    \
            f32x4 aZ  = {db_z, db_z, db_z, db_z};                                    \
            f32x4 aXN = {db_xn, db_xn, db_xn, db_xn};                                \
            f32x4 aHN = {db_hn, db_hn, db_hn, db_hn};                                \
            aR  = mfma16(ah0, wd_r[0], aR);   aR  = mfma16(ah1, wd_r[1], aR);        \
            aR  = mfma16(ah2, wd_r[2], aR);   aR  = mfma16(ah3, wd_r[3], aR);        \
            aZ  = mfma16(ah0, wd_z[0], aZ);   aZ  = mfma16(ah1, wd_z[1], aZ);        \
            aZ  = mfma16(ah2, wd_z[2], aZ);   aZ  = mfma16(ah3, wd_z[3], aZ);        \
            aXN = mfma16(ah0, wd_xn[0], aXN); aXN = mfma16(ah1, wd_xn[1], aXN);      \
            aXN = mfma16(ah2, wd_xn[2], aXN); aXN = mfma16(ah3, wd_xn[3], aXN);      \
            aHN = mfma16(ah0, wd_hn[0], aHN); aHN = mfma16(ah1, wd_hn[1], aHN);      \
            aHN = mfma16(ah2, wd_hn[2], aHN); aHN = mfma16(ah3, wd_hn[3], aHN);      \
            _Pragma("unroll")                                                        \
            for (int r = 0; r < 4; r++) {                                            \
                float ea = fexp2n(aR[r]), eb = fexp2n(aZ[r]);                        \
                float s1 = 1.0f + ea, s2 = 1.0f + eb;                                \
                float R = __builtin_amdgcn_rcpf(s1 * s2);                            \
                float rg = s2 * R, zg = s1 * R;                                      \
                float ec = fexp2n(2.0f * (aXN[r] + rg * aHN[r]));                    \
                float ng = (1.0f - ec) * __builtin_amdgcn_rcpf(1.0f + ec);           \
                float h = ng + zg * (ho[r] - ng);                                    \
                ho[r] = h;                                                           \
                *(f16*)(HS(OBUF) + wb[r]) = (f16)h;                                  \
            }                                                                        \
        } while (0)

        DEC_STEP(1, 0);            // step 1
        for (int t = 2; t < 64; t += 2) {
            DEC_STEP(0, 1);
            DEC_STEP(1, 0);
        }
#undef DEC_STEP
    }

    // ================= heads (wstage dead -> pn_s region free) =================
    __syncthreads();   // all wstage/h traffic done before pn_s writes
    #pragma unroll
    for (int r = 0; r < 4; r++) {
        pn_s[quad * 4 + r][wv * 16 + nl] = zc[r];        // z_cnn
        pn_s[quad * 4 + r][128 + j0 + nl] = ho[r];       // z_pn
    }
    __syncthreads();

    const int rr = tid & 15, og = tid >> 4;   // og 0..31
    const float4* pr4 = (const float4*)(&pn_s[rr][0]);
    for (int o = og; o < 79; o += 32) {
        const float* wrow_p = (o < 78) ? (dis_w + o * 256) : value_w;
        float acc = (o < 78) ? dis_b[o] : value_b[0];
        const float4* wr4 = (const float4*)wrow_p;
        #pragma unroll 8
        for (int k = 0; k < 64; k++) {
            float4 a = wr4[k], b = pr4[k];
            acc += a.x * b.x + a.y * b.y + a.z * b.z + a.w * b.w;
        }
        if (o < 78) out[(size_t)(row0 + rr) * 78 + o] = acc;
        else        out[(size_t)8192 * 78 + row0 + rr] = acc;
    }
#undef HS
}

extern "C" void kernel_launch(void* const* d_in, const int* in_sizes, int n_in,
                              void* d_out, int out_size, void* d_ws, size_t ws_size,
                              hipStream_t stream)
{
    (void)in_sizes; (void)n_in; (void)out_size; (void)ws_size;
    const float* cnn  = (const float*)d_in[0];
    const float* lin  = (const float*)d_in[1];
    const float* c1w  = (const float*)d_in[2];
    const float* c1b  = (const float*)d_in[3];
    const float* c2w  = (const float*)d_in[4];
    const float* c2b  = (const float*)d_in[5];
    const float* fcw  = (const float*)d_in[6];
    const float* fcb  = (const float*)d_in[7];
    const float* eWih = (const float*)d_in[8];
    const float* eWhh = (const float*)d_in[9];
    const float* ebih = (const float*)d_in[10];
    const float* ebhh = (const float*)d_in[11];
    const float* dWih = (const float*)d_in[12];
    const float* dWhh = (const float*)d_in[13];
    const float* dbih = (const float*)d_in[14];
    const float* dbhh = (const float*)d_in[15];
    const float* disw = (const float*)d_in[16];
    const float* disb = (const float*)d_in[17];
    const float* vw   = (const float*)d_in[18];
    const float* vb   = (const float*)d_in[19];
    char* ws = (char*)d_ws;
    float* out = (float*)d_out;

    hipLaunchKernelGGL(k_prep, dim3(128), dim3(256), 0, stream,
                       eWih, eWhh, ebih, ebhh, dWih, dWhh, dbih, dbhh,
                       c1w, c2w, fcw, ws);
    hipLaunchKernelGGL(k_gru, dim3(512), dim3(512), 0, stream,
                       cnn, lin, c1b, c2b, fcb, ws, disw, disb, vw, vb, out);
}

// Round 10
// 340.570 us; speedup vs baseline: 1.0842x; 1.0842x over previous
//
#include <hip/hip_runtime.h>

typedef _Float16 f16;
typedef _Float16 f16x8 __attribute__((ext_vector_type(8)));
typedef float f32x4 __attribute__((ext_vector_type(4)));

// ---- workspace layout (bytes) ----
#define WS_EWIH 4194304                // enc Wih f16 [384][32] (k>=29 zero)
#define WS_EWHH 4218880                // enc Whh f16 [384][128]
#define WS_DWC  4317184                // dec combined f16 [512][128]
#define WS_DWHH 4448256                // dec Whh f16 [384][128]
#define WS_BIAS 4546560                // f32[1024]
#define WS_W1F  4550656                // conv1 B-frags f16 [9][16][32]
#define WS_W2F  4559872                // conv2 B-frags f16 [2][32][32]
#define WS_FCWF 4563968                // fc weights f16 [128][128]

static __device__ __forceinline__ f32x4 mfma16(f16x8 a, f16x8 b, f32x4 c) {
    return __builtin_amdgcn_mfma_f32_16x16x32_f16(a, b, c, 0, 0, 0);
}
static __device__ __forceinline__ float fexp2n(float x) {   // 2^(-x*log2e)
    return __builtin_amdgcn_exp2f(x * -1.4426950408889634f);
}

// ---------------- prep: f32 -> f16 packs ----------------
__global__ void k_prep(const float* __restrict__ eWih, const float* __restrict__ eWhh,
                       const float* __restrict__ ebih, const float* __restrict__ ebhh,
                       const float* __restrict__ dWih, const float* __restrict__ dWhh,
                       const float* __restrict__ dbih, const float* __restrict__ dbhh,
                       const float* __restrict__ w1, const float* __restrict__ w2,
                       const float* __restrict__ fcw,
                       char* __restrict__ ws)
{
    f16* ewih = (f16*)(ws + WS_EWIH);
    f16* ewhh = (f16*)(ws + WS_EWHH);
    f16* dwc  = (f16*)(ws + WS_DWC);
    f16* dwhh = (f16*)(ws + WS_DWHH);
    float* bias = (float*)(ws + WS_BIAS);
    f16* w1f = (f16*)(ws + WS_W1F);
    f16* w2f = (f16*)(ws + WS_W2F);
    f16* fcwf = (f16*)(ws + WS_FCWF);
    const int total = 12288 + 49152 + 65536 + 49152 + 1024 + 4608 + 2048 + 16384;
    for (int i = blockIdx.x * 256 + threadIdx.x; i < total; i += gridDim.x * 256) {
        int j = i;
        if (j < 12288) { int g = j >> 5, k = j & 31;
            ewih[j] = (f16)((k < 29) ? eWih[g * 29 + k] : 0.0f); continue; }
        j -= 12288;
        if (j < 49152) { ewhh[j] = (f16)eWhh[j]; continue; }
        j -= 49152;
        if (j < 65536) { int row = j >> 7, k = j & 127; float v;
            if (row < 256)      v = dWih[row * 128 + k] + dWhh[row * 128 + k];
            else if (row < 384) v = dWih[row * 128 + k];
            else                v = dWhh[(row - 128) * 128 + k];
            dwc[j] = (f16)v; continue; }
        j -= 65536;
        if (j < 49152) { dwhh[j] = (f16)dWhh[j]; continue; }
        j -= 49152;
        if (j < 1024) {
            if (j < 256)        bias[j] = ebih[j] + ebhh[j];
            else if (j < 384)   bias[j] = ebih[j];
            else if (j < 512)   bias[j] = ebhh[j - 128];
            else if (j < 768)   bias[j] = dbih[j - 512] + dbhh[j - 512];
            else if (j < 896)   bias[j] = dbih[j - 512];
            else                bias[j] = dbhh[j - 640];
            continue; }
        j -= 1024;
        if (j < 4608) {   // w1f[kk][co][k]: w1 (16,27,3,3) OIHW; k>=27 -> 0
            int kk = j >> 9, rem = j & 511, co = rem >> 5, k = rem & 31;
            w1f[j] = (f16)((k < 27) ? w1[co * 243 + k * 9 + kk] : 0.0f); continue; }
        j -= 4608;
        if (j < 2048) {   // w2f[s][co][k]
            int s = j >> 10, rem = j & 1023, co = rem >> 5, k = rem & 31;
            int kk2 = 2 * s + (k >= 16), ci = k & 15;
            w2f[j] = (f16)w2[co * 64 + ci * 4 + kk2]; continue; }
        j -= 2048;
        fcwf[j] = (f16)fcw[j];
    }
}

// ---------------- fused CNN + GRU + heads: 512 threads, 32 rows/block, 2 groups ----------------
// KEY CHANGE vs r6/r8: each block processes TWO independent 16-row batch groups (A,B)
// interleaved in one step loop. The (shared!) weight frags are fetched once per
// double-step (halving per-work L1/L2 remat traffic), and the two groups' dependency
// chains are independent (2x ILP between barriers, half the barriers per work).
// Grid 256 x 512thr = 1 block/CU, 8 waves each carrying 2 instruction streams.
__global__ __launch_bounds__(512, 2) void k_gru(
    const float* __restrict__ cin,
    const float* __restrict__ lin,
    const float* __restrict__ b1, const float* __restrict__ b2,
    const float* __restrict__ fcb,
    const char* __restrict__ ws,
    const float* __restrict__ dis_w, const float* __restrict__ dis_b,
    const float* __restrict__ value_w, const float* __restrict__ value_b,
    float* __restrict__ out)
{
    __shared__ __align__(16) char smem[62976];
    // [0,16384)      h bufs: A0,A1,B0,B1 (4 x 4096, XOR swizzle); CNN alias a1f[32][9][24]=13824
    // [16384,20480)  x bufs: A0,A1,B0,B1 (4 x 1024)
    // [20480,54272)  pn_s [32][264] f32 (heads only)
    // [54272,62976)  vf [32][136] f16 (CNN only)
    f16 (*a1f)[9][24]  = (f16(*)[9][24])(smem);
    float (*pn_s)[264] = (float(*)[264])(smem + 20480);
    f16 (*vf)[136]     = (f16(*)[136])(smem + 54272);
#define HSA(B) (smem + (B) * 4096)
#define HSB(B) (smem + 8192 + (B) * 4096)
#define XSA(B) ((f16(*)[32])(smem + 16384 + (B) * 1024))
#define XSB(B) ((f16(*)[32])(smem + 18432 + (B) * 1024))

    const int tid = threadIdx.x;
    const int wv = tid >> 6;
    const int lane = tid & 63;
    const int nl = lane & 15;
    const int quad = lane >> 4;
    const int j0 = wv * 16;
    const int row0 = blockIdx.x * 32;

    const f16* ewih = (const f16*)(ws + WS_EWIH);
    const f16* ewhh = (const f16*)(ws + WS_EWHH);
    const f16* dwc  = (const f16*)(ws + WS_DWC);
    const f16* dwhh = (const f16*)(ws + WS_DWHH);
    const float* bias = (const float*)(ws + WS_BIAS);
    const f16* w1f = (const f16*)(ws + WS_W1F);
    const f16* w2f = (const f16*)(ws + WS_W2F);
    const f16* fcwf = (const f16*)(ws + WS_FCWF);

    float zc[2][4];   // z_cnn slices (both groups), register-resident until heads

    // ================= CNN prologue (32 images = this block's rows) =================
    {
        float b1v = b1[nl];
        for (int p2 = wv; p2 < 18; p2 += 8) {
            int g = p2 / 9, p = p2 % 9;
            int oy = p / 3, ox = p % 3;
            const float* imgp = cin + (size_t)(row0 + g * 16 + nl) * 1728 + quad * 8;
            f32x4 acc = {b1v, b1v, b1v, b1v};
            #pragma unroll
            for (int kk = 0; kk < 9; kk++) {
                f16x8 bw = *(const f16x8*)(w1f + (kk * 16 + nl) * 32 + quad * 8);
                int pix = (2 * oy + kk / 3) * 8 + (2 * ox + kk % 3);
                const float* s = imgp + pix * 27;
                f16x8 a;
                #pragma unroll
                for (int jj = 0; jj < 8; jj++) a[jj] = (f16)s[jj];
                acc = mfma16(a, bw, acc);
            }
            #pragma unroll
            for (int r = 0; r < 4; r++)
                a1f[g * 16 + quad * 4 + r][p][nl] = (f16)fmaxf(acc[r], 0.0f);
        }
        __syncthreads();
        for (int u = wv; u < 16; u += 8) {
            int g = u >> 3, pos = (u & 7) >> 1, nt = u & 1;
            int y = pos >> 1, x = pos & 1;
            float bv = b2[nt * 16 + nl];
            f32x4 acc = {bv, bv, bv, bv};
            #pragma unroll
            for (int s = 0; s < 2; s++) {
                int kk2 = 2 * s + (quad >> 1);
                int pos1 = (y + (kk2 >> 1)) * 3 + (x + (kk2 & 1));
                f16x8 a = *(const f16x8*)(&a1f[g * 16 + nl][pos1][(quad & 1) * 8]);
                f16x8 b = *(const f16x8*)(w2f + ((size_t)s * 32 + nt * 16 + nl) * 32 + quad * 8);
                acc = mfma16(a, b, acc);
            }
            #pragma unroll
            for (int r = 0; r < 4; r++)
                vf[g * 16 + quad * 4 + r][(nt * 16 + nl) * 4 + (y * 2 + x)] = (f16)fmaxf(acc[r], 0.0f);
        }
        __syncthreads();
        #pragma unroll
        for (int g = 0; g < 2; g++) {
            int o = wv * 16 + nl;
            float bv = fcb[o];
            f32x4 acc = {bv, bv, bv, bv};
            #pragma unroll
            for (int kt = 0; kt < 4; kt++) {
                f16x8 a = *(const f16x8*)(&vf[g * 16 + nl][kt * 32 + quad * 8]);
                f16x8 b = *(const f16x8*)(fcwf + o * 128 + kt * 32 + quad * 8);
                acc = mfma16(a, b, acc);
            }
            #pragma unroll
            for (int r = 0; r < 4; r++)
                zc[g][r] = fmaxf(acc[r], 0.0f);
        }
        __syncthreads();   // a1f dead; safe to zero h bufs below
    }

    for (int i = tid; i < 8192; i += 512) ((f16*)smem)[i] = (f16)0.0f;

    // LDS address constants (XOR swizzle; same geometry both groups)
    const int lane7 = nl & 7;
    int rb[4], wb[4];
    #pragma unroll
    for (int kt = 0; kt < 4; kt++)
        rb[kt] = nl * 256 + (((4 * kt + quad) ^ lane7) << 4);
    #pragma unroll
    for (int r = 0; r < 4; r++) {
        int row = quad * 4 + r;
        wb[r] = row * 256 + ((((2 * wv + (nl >> 3)) ^ (row & 7)) << 3) + lane7) * 2;
    }

    float hoA[4], hoB[4];
    #pragma unroll
    for (int r = 0; r < 4; r++) { hoA[r] = 0.0f; hoB[r] = 0.0f; }

    const int xr = tid >> 5, xc = tid & 31;   // x staging: 16 rows x 32 cols per group
    const bool xok = (xc < 29);
    const size_t lin_baseA = (size_t)(row0 + xr) * 1856 + xc;
    const size_t lin_baseB = (size_t)(row0 + 16 + xr) * 1856 + xc;

    // elementwise GRU update for one 4-row slice
#define EW4(aR, aZ, aXN, aHN, ho, HDST)                                              \
        _Pragma("unroll")                                                            \
        for (int r = 0; r < 4; r++) {                                                \
            float ea = fexp2n(aR[r]), eb = fexp2n(aZ[r]);                            \
            float s1 = 1.0f + ea, s2 = 1.0f + eb;                                    \
            float R = __builtin_amdgcn_rcpf(s1 * s2);                                \
            float rg = s2 * R, zg = s1 * R;                                          \
            float ec = fexp2n(2.0f * (aXN[r] + rg * aHN[r]));                        \
            float ng = (1.0f - ec) * __builtin_amdgcn_rcpf(1.0f + ec);               \
            float h = ng + zg * (ho[r] - ng);                                        \
            ho[r] = h;                                                               \
            *(f16*)((HDST) + wb[r]) = (f16)h;                                        \
        }

    // ================= encoder =================
    {
        float eb_r, eb_z, eb_xn, eb_hn;
        { int c = j0 + nl;
          eb_r = bias[c]; eb_z = bias[128 + c]; eb_xn = bias[256 + c]; eb_hn = bias[384 + c]; }
        f16x8 we_r[4], we_z[4], we_hn[4], we_xr, we_xz, we_xn;
        { int gr = j0 + nl;
          #pragma unroll
          for (int kt = 0; kt < 4; kt++) {
              we_r[kt]  = *(const f16x8*)(ewhh + gr * 128 + kt * 32 + quad * 8);
              we_z[kt]  = *(const f16x8*)(ewhh + (128 + gr) * 128 + kt * 32 + quad * 8);
              we_hn[kt] = *(const f16x8*)(ewhh + (256 + gr) * 128 + kt * 32 + quad * 8);
          }
          we_xr = *(const f16x8*)(ewih + gr * 32 + quad * 8);
          we_xz = *(const f16x8*)(ewih + (128 + gr) * 32 + quad * 8);
          we_xn = *(const f16x8*)(ewih + (256 + gr) * 32 + quad * 8);
        }

        float xvA = xok ? lin[lin_baseA] : 0.0f;
        float xvB = xok ? lin[lin_baseB] : 0.0f;

#define ENC_STEP(BUF, OBUF, TN)                                                      \
        do {                                                                         \
            XSA(BUF)[xr][xc] = (f16)xvA;                                             \
            XSB(BUF)[xr][xc] = (f16)xvB;                                             \
            __syncthreads();                                                         \
            f16x8 axA = *(const f16x8*)(&XSA(BUF)[nl][quad * 8]);                    \
            f16x8 axB = *(const f16x8*)(&XSB(BUF)[nl][quad * 8]);                    \
            f16x8 aA0 = *(const f16x8*)(HSA(BUF) + rb[0]);                           \
            f16x8 aA1 = *(const f16x8*)(HSA(BUF) + rb[1]);                           \
            f16x8 aA2 = *(const f16x8*)(HSA(BUF) + rb[2]);                           \
            f16x8 aA3 = *(const f16x8*)(HSA(BUF) + rb[3]);                           \
            f16x8 aB0 = *(const f16x8*)(HSB(BUF) + rb[0]);                           \
            f16x8 aB1 = *(const f16x8*)(HSB(BUF) + rb[1]);                           \
            f16x8 aB2 = *(const f16x8*)(HSB(BUF) + rb[2]);                           \
            f16x8 aB3 = *(const f16x8*)(HSB(BUF) + rb[3]);                           \
            if ((TN) < 64) {                                                         \
                xvA = xok ? lin[lin_baseA + (TN) * 29] : 0.0f;                       \
                xvB = xok ? lin[lin_baseB + (TN) * 29] : 0.0f;                       \
            }                                                                        \
            f32x4 RA = {eb_r, eb_r, eb_r, eb_r},  RB = RA;                           \
            f32x4 ZA = {eb_z, eb_z, eb_z, eb_z},  ZB = ZA;                           \
            f32x4 XNA = {eb_xn, eb_xn, eb_xn, eb_xn}, XNB = XNA;                     \
            f32x4 HNA = {eb_hn, eb_hn, eb_hn, eb_hn}, HNB = HNA;                     \
            RA  = mfma16(axA, we_xr, RA);   RB  = mfma16(axB, we_xr, RB);            \
            ZA  = mfma16(axA, we_xz, ZA);   ZB  = mfma16(axB, we_xz, ZB);            \
            XNA = mfma16(axA, we_xn, XNA);  XNB = mfma16(axB, we_xn, XNB);           \
            RA  = mfma16(aA0, we_r[0], RA);   RB  = mfma16(aB0, we_r[0], RB);        \
            RA  = mfma16(aA1, we_r[1], RA);   RB  = mfma16(aB1, we_r[1], RB);        \
            RA  = mfma16(aA2, we_r[2], RA);   RB  = mfma16(aB2, we_r[2], RB);        \
            RA  = mfma16(aA3, we_r[3], RA);   RB  = mfma16(aB3, we_r[3], RB);        \
            ZA  = mfma16(aA0, we_z[0], ZA);   ZB  = mfma16(aB0, we_z[0], ZB);        \
            ZA  = mfma16(aA1, we_z[1], ZA);   ZB  = mfma16(aB1, we_z[1], ZB);        \
            ZA  = mfma16(aA2, we_z[2], ZA);   ZB  = mfma16(aB2, we_z[2], ZB);        \
            ZA  = mfma16(aA3, we_z[3], ZA);   ZB  = mfma16(aB3, we_z[3], ZB);        \
            HNA = mfma16(aA0, we_hn[0], HNA); HNB = mfma16(aB0, we_hn[0], HNB);      \
            HNA = mfma16(aA1, we_hn[1], HNA); HNB = mfma16(aB1, we_hn[1], HNB);      \
            HNA = mfma16(aA2, we_hn[2], HNA); HNB = mfma16(aB2, we_hn[2], HNB);      \
            HNA = mfma16(aA3, we_hn[3], HNA); HNB = mfma16(aB3, we_hn[3], HNB);      \
            EW4(RA, ZA, XNA, HNA, hoA, HSA(OBUF))                                    \
            EW4(RB, ZB, XNB, HNB, hoB, HSB(OBUF))                                    \
        } while (0)

        for (int t = 0; t < 64; t += 2) {
            ENC_STEP(0, 1, t + 1);
            ENC_STEP(1, 0, t + 2);
        }
#undef ENC_STEP
    }

    // ================= decoder =================
    float db_r, db_z, db_xn, db_hn;
    { int c = j0 + nl;
      db_r = bias[512 + c]; db_z = bias[640 + c]; db_xn = bias[768 + c]; db_hn = bias[896 + c]; }

    // step 0: xin = 0 -> gx = bih; Whh frags loaded once, shared by both groups
    {
        __syncthreads();
        f16x8 aA0 = *(const f16x8*)(HSA(0) + rb[0]);
        f16x8 aA1 = *(const f16x8*)(HSA(0) + rb[1]);
        f16x8 aA2 = *(const f16x8*)(HSA(0) + rb[2]);
        f16x8 aA3 = *(const f16x8*)(HSA(0) + rb[3]);
        f16x8 aB0 = *(const f16x8*)(HSB(0) + rb[0]);
        f16x8 aB1 = *(const f16x8*)(HSB(0) + rb[1]);
        f16x8 aB2 = *(const f16x8*)(HSB(0) + rb[2]);
        f16x8 aB3 = *(const f16x8*)(HSB(0) + rb[3]);
        int gr = j0 + nl;
        f32x4 RA = {db_r, db_r, db_r, db_r},  RB = RA;
        f32x4 ZA = {db_z, db_z, db_z, db_z},  ZB = ZA;
        f32x4 XNA = {db_xn, db_xn, db_xn, db_xn}, XNB = XNA;
        f32x4 HNA = {db_hn, db_hn, db_hn, db_hn}, HNB = HNA;
        #pragma unroll
        for (int kt = 0; kt < 4; kt++) {
            f16x8 b0 = *(const f16x8*)(dwhh + gr * 128 + kt * 32 + quad * 8);
            f16x8 b1 = *(const f16x8*)(dwhh + (128 + gr) * 128 + kt * 32 + quad * 8);
            f16x8 b2 = *(const f16x8*)(dwhh + (256 + gr) * 128 + kt * 32 + quad * 8);
            f16x8 aA = (kt == 0) ? aA0 : (kt == 1) ? aA1 : (kt == 2) ? aA2 : aA3;
            f16x8 aB = (kt == 0) ? aB0 : (kt == 1) ? aB1 : (kt == 2) ? aB2 : aB3;
            RA  = mfma16(aA, b0, RA);   RB  = mfma16(aB, b0, RB);
            ZA  = mfma16(aA, b1, ZA);   ZB  = mfma16(aB, b1, ZB);
            HNA = mfma16(aA, b2, HNA);  HNB = mfma16(aB, b2, HNB);
        }
        EW4(RA, ZA, XNA, HNA, hoA, HSA(1))
        EW4(RB, ZB, XNB, HNB, hoB, HSB(1))
    }
    // steps 1..63: xin == h -> combined weights, shared by both groups
    {
        f16x8 wd_r[4], wd_z[4], wd_xn[4], wd_hn[4];
        { int gr = j0 + nl;
          #pragma unroll
          for (int kt = 0; kt < 4; kt++) {
              wd_r[kt]  = *(const f16x8*)(dwc + gr * 128 + kt * 32 + quad * 8);
              wd_z[kt]  = *(const f16x8*)(dwc + (128 + gr) * 128 + kt * 32 + quad * 8);
              wd_xn[kt] = *(const f16x8*)(dwc + (256 + gr) * 128 + kt * 32 + quad * 8);
              wd_hn[kt] = *(const f16x8*)(dwc + (384 + gr) * 128 + kt * 32 + quad * 8);
          }
        }

#define DEC_STEP(BUF, OBUF)                                                          \
        do {                                                                         \
            __syncthreads();                                                         \
            f16x8 aA0 = *(const f16x8*)(HSA(BUF) + rb[0]);                           \
            f16x8 aA1 = *(const f16x8*)(HSA(BUF) + rb[1]);                           \
            f16x8 aA2 = *(const f16x8*)(HSA(BUF) + rb[2]);                           \
            f16x8 aA3 = *(const f16x8*)(HSA(BUF) + rb[3]);                           \
            f16x8 aB0 = *(const f16x8*)(HSB(BUF) + rb[0]);                           \
            f16x8 aB1 = *(const f16x8*)(HSB(BUF) + rb[1]);                           \
            f16x8 aB2 = *(const f16x8*)(HSB(BUF) + rb[2]);                           \
            f16x8 aB3 = *(const f16x8*)(HSB(BUF) + rb[3]);                           \
            f32x4 RA = {db_r, db_r, db_r, db_r},  RB = RA;                           \
            f32x4 ZA = {db_z, db_z, db_z, db_z},  ZB = ZA;                           \
            f32x4 XNA = {db_xn, db_xn, db_xn, db_xn}, XNB = XNA;                     \
            f32x4 HNA = {db_hn, db_hn, db_hn, db_hn}, HNB = HNA;                     \
            RA  = mfma16(aA0, wd_r[0], RA);   RB  = mfma16(aB0, wd_r[0], RB);        \
            RA  = mfma16(aA1, wd_r[1], RA);   RB  = mfma16(aB1, wd_r[1], RB);        \
            RA  = mfma16(aA2, wd_r[2], RA);   RB  = mfma16(aB2, wd_r[2], RB);        \
            RA  = mfma16(aA3, wd_r[3], RA);   RB  = mfma16(aB3, wd_r[3], RB);        \
            ZA  = mfma16(aA0, wd_z[0], ZA);   ZB  = mfma16(aB0, wd_z[0], ZB);        \
            ZA  = mfma16(aA1, wd_z[1], ZA);   ZB  = mfma16(aB1, wd_z[1], ZB);        \
            ZA  = mfma16(aA2, wd_z[2], ZA);   ZB  = mfma16(aB2, wd_z[2], ZB);        \
            ZA  = mfma16(aA3, wd_z[3], ZA);   ZB  = mfma16(aB3, wd_z[3], ZB);        \
            XNA = mfma16(aA0, wd_xn[0], XNA); XNB = mfma16(aB0, wd_xn[0], XNB);      \
            XNA = mfma16(aA1, wd_xn[1], XNA); XNB = mfma16(aB1, wd_xn[1], XNB);      \
            XNA = mfma16(aA2, wd_xn[2], XNA); XNB = mfma16(aB2, wd_xn[2], XNB);      \
            XNA = mfma16(aA3, wd_xn[3], XNA); XNB = mfma16(aB3, wd_xn[3], XNB);      \
            HNA = mfma16(aA0, wd_hn[0], HNA); HNB = mfma16(aB0, wd_hn[0], HNB);      \
            HNA = mfma16(aA1, wd_hn[1], HNA); HNB = mfma16(aB1, wd_hn[1], HNB);      \
            HNA = mfma16(aA2, wd_hn[2], HNA); HNB = mfma16(aB2, wd_hn[2], HNB);      \
            HNA = mfma16(aA3, wd_hn[3], HNA); HNB = mfma16(aB3, wd_hn[3], HNB);      \
            EW4(RA, ZA, XNA, HNA, hoA, HSA(OBUF))                                    \
            EW4(RB, ZB, XNB, HNB, hoB, HSB(OBUF))                                    \
        } while (0)

        DEC_STEP(1, 0);            // step 1
        for (int t = 2; t < 64; t += 2) {
            DEC_STEP(0, 1);
            DEC_STEP(1, 0);
        }
#undef DEC_STEP
    }

    // ================= heads =================
    __syncthreads();
    #pragma unroll
    for (int r = 0; r < 4; r++) {
        pn_s[quad * 4 + r][wv * 16 + nl] = zc[0][r];
        pn_s[16 + quad * 4 + r][wv * 16 + nl] = zc[1][r];
        pn_s[quad * 4 + r][128 + j0 + nl] = hoA[r];
        pn_s[16 + quad * 4 + r][128 + j0 + nl] = hoB[r];
    }
    __syncthreads();

    const int rr = tid & 31, og = tid >> 5;   // og 0..15
    const float4* pr4 = (const float4*)(&pn_s[rr][0]);
    for (int o = og; o < 79; o += 16) {
        const float* wrow_p = (o < 78) ? (dis_w + o * 256) : value_w;
        float acc = (o < 78) ? dis_b[o] : value_b[0];
        const float4* wr4 = (const float4*)wrow_p;
        #pragma unroll 8
        for (int k = 0; k < 64; k++) {
            float4 a = wr4[k], b = pr4[k];
            acc += a.x * b.x + a.y * b.y + a.z * b.z + a.w * b.w;
        }
        if (o < 78) out[(size_t)(row0 + rr) * 78 + o] = acc;
        else        out[(size_t)8192 * 78 + row0 + rr] = acc;
    }
#undef HSA
#undef HSB
#undef XSA
#undef XSB
#undef EW4
}

extern "C" void kernel_launch(void* const* d_in, const int* in_sizes, int n_in,
                              void* d_out, int out_size, void* d_ws, size_t ws_size,
                              hipStream_t stream)
{
    (void)in_sizes; (void)n_in; (void)out_size; (void)ws_size;
    const float* cnn  = (const float*)d_in[0];
    const float* lin  = (const float*)d_in[1];
    const float* c1w  = (const float*)d_in[2];
    const float* c1b  = (const float*)d_in[3];
    const float* c2w  = (const float*)d_in[4];
    const float* c2b  = (const float*)d_in[5];
    const float* fcw  = (const float*)d_in[6];
    const float* fcb  = (const float*)d_in[7];
    const float* eWih = (const float*)d_in[8];
    const float* eWhh = (const float*)d_in[9];
    const float* ebih = (const float*)d_in[10];
    const float* ebhh = (const float*)d_in[11];
    const float* dWih = (const float*)d_in[12];
    const float* dWhh = (const float*)d_in[13];
    const float* dbih = (const float*)d_in[14];
    const float* dbhh = (const float*)d_in[15];
    const float* disw = (const float*)d_in[16];
    const float* disb = (const float*)d_in[17];
    const float* vw   = (const float*)d_in[18];
    const float* vb   = (const float*)d_in[19];
    char* ws = (char*)d_ws;
    float* out = (float*)d_out;

    hipLaunchKernelGGL(k_prep, dim3(128), dim3(256), 0, stream,
                       eWih, eWhh, ebih, ebhh, dWih, dWhh, dbih, dbhh,
                       c1w, c2w, fcw, ws);
    hipLaunchKernelGGL(k_gru, dim3(256), dim3(512), 0, stream,
                       cnn, lin, c1b, c2b, fcb, ws, disw, disb, vw, vb, out);
}

// Round 11
// 332.704 us; speedup vs baseline: 1.1099x; 1.0236x over previous
//
#include <hip/hip_runtime.h>

typedef _Float16 f16;
typedef _Float16 f16x8 __attribute__((ext_vector_type(8)));
typedef float f32x4 __attribute__((ext_vector_type(4)));

// ---- workspace layout (bytes) ----
#define WS_EWIH 4194304                // enc Wih f16 [384][32] (k>=29 zero)
#define WS_EWHH 4218880                // enc Whh f16 [384][128]
#define WS_DWC  4317184                // dec combined f16 [512][128]
#define WS_DWHH 4448256                // dec Whh f16 [384][128]
#define WS_BIAS 4546560                // f32[1024]
#define WS_W1F  4550656                // conv1 B-frags f16 [9][16][32]
#define WS_W2F  4559872                // conv2 B-frags f16 [2][32][32]
#define WS_FCWF 4563968                // fc weights f16 [128][128]

static __device__ __forceinline__ f32x4 mfma16(f16x8 a, f16x8 b, f32x4 c) {
    return __builtin_amdgcn_mfma_f32_16x16x32_f16(a, b, c, 0, 0, 0);
}
static __device__ __forceinline__ float fexp2n(float x) {   // 2^(-x*log2e)
    return __builtin_amdgcn_exp2f(x * -1.4426950408889634f);
}

// ---------------- prep: f32 -> f16 packs ----------------
__global__ void k_prep(const float* __restrict__ eWih, const float* __restrict__ eWhh,
                       const float* __restrict__ ebih, const float* __restrict__ ebhh,
                       const float* __restrict__ dWih, const float* __restrict__ dWhh,
                       const float* __restrict__ dbih, const float* __restrict__ dbhh,
                       const float* __restrict__ w1, const float* __restrict__ w2,
                       const float* __restrict__ fcw,
                       char* __restrict__ ws)
{
    f16* ewih = (f16*)(ws + WS_EWIH);
    f16* ewhh = (f16*)(ws + WS_EWHH);
    f16* dwc  = (f16*)(ws + WS_DWC);
    f16* dwhh = (f16*)(ws + WS_DWHH);
    float* bias = (float*)(ws + WS_BIAS);
    f16* w1f = (f16*)(ws + WS_W1F);
    f16* w2f = (f16*)(ws + WS_W2F);
    f16* fcwf = (f16*)(ws + WS_FCWF);
    const int total = 12288 + 49152 + 65536 + 49152 + 1024 + 4608 + 2048 + 16384;
    for (int i = blockIdx.x * 256 + threadIdx.x; i < total; i += gridDim.x * 256) {
        int j = i;
        if (j < 12288) { int g = j >> 5, k = j & 31;
            ewih[j] = (f16)((k < 29) ? eWih[g * 29 + k] : 0.0f); continue; }
        j -= 12288;
        if (j < 49152) { ewhh[j] = (f16)eWhh[j]; continue; }
        j -= 49152;
        if (j < 65536) { int row = j >> 7, k = j & 127; float v;
            if (row < 256)      v = dWih[row * 128 + k] + dWhh[row * 128 + k];
            else if (row < 384) v = dWih[row * 128 + k];
            else                v = dWhh[(row - 128) * 128 + k];
            dwc[j] = (f16)v; continue; }
        j -= 65536;
        if (j < 49152) { dwhh[j] = (f16)dWhh[j]; continue; }
        j -= 49152;
        if (j < 1024) {
            if (j < 256)        bias[j] = ebih[j] + ebhh[j];
            else if (j < 384)   bias[j] = ebih[j];
            else if (j < 512)   bias[j] = ebhh[j - 128];
            else if (j < 768)   bias[j] = dbih[j - 512] + dbhh[j - 512];
            else if (j < 896)   bias[j] = dbih[j - 512];
            else                bias[j] = dbhh[j - 640];
            continue; }
        j -= 1024;
        if (j < 4608) {   // w1f[kk][co][k]: w1 (16,27,3,3) OIHW; k>=27 -> 0
            int kk = j >> 9, rem = j & 511, co = rem >> 5, k = rem & 31;
            w1f[j] = (f16)((k < 27) ? w1[co * 243 + k * 9 + kk] : 0.0f); continue; }
        j -= 4608;
        if (j < 2048) {   // w2f[s][co][k]
            int s = j >> 10, rem = j & 1023, co = rem >> 5, k = rem & 31;
            int kk2 = 2 * s + (k >= 16), ci = k & 15;
            w2f[j] = (f16)w2[co * 64 + ci * 4 + kk2]; continue; }
        j -= 2048;
        fcwf[j] = (f16)fcw[j];
    }
}

// ---------------- fused CNN + GRU + heads: 512 threads, 16 rows/block ----------------
// Best-known configuration (round 6, 331.7 us total): CNN prologue writes z_cnn
// directly into pn_s cols 0..127; 2 blocks/CU, 16 waves/CU. Subsequent rounds
// (pinning, XOR swizzle, LDS-staged weights, 2-group ILP) all landed 215-233 us
// on k_gru -> latency/barrier-cadence plateau, so this is the keeper.
__global__ __launch_bounds__(512, 4) void k_gru(
    const float* __restrict__ cin,
    const float* __restrict__ lin,
    const float* __restrict__ b1, const float* __restrict__ b2,
    const float* __restrict__ fcb,
    const char* __restrict__ ws,
    const float* __restrict__ dis_w, const float* __restrict__ dis_b,
    const float* __restrict__ value_w, const float* __restrict__ value_b,
    float* __restrict__ out)
{
    __shared__ __align__(16) char smem[32000];
    f16 (*h_s)[16][136]  = (f16(*)[16][136])(smem);            // 8704 B
    f16 (*x_s)[16][32]   = (f16(*)[16][32])(smem + 8704);      // 2048 B
    float (*pn_s)[264]   = (float(*)[264])(smem + 10752);      // 16896 B
    f16 (*a1f)[9][24]    = (f16(*)[9][24])(smem);              // 6912 B, aliases h_s (CNN phase only)
    f16 (*vf)[136]       = (f16(*)[136])(smem + 27648);        // 4352 B

    const int tid = threadIdx.x;
    const int wv = tid >> 6;
    const int lane = tid & 63;
    const int nl = lane & 15;
    const int quad = lane >> 4;
    const int j0 = wv * 16;
    const int row0 = blockIdx.x * 16;

    const f16* ewih = (const f16*)(ws + WS_EWIH);
    const f16* ewhh = (const f16*)(ws + WS_EWHH);
    const f16* dwc  = (const f16*)(ws + WS_DWC);
    const f16* dwhh = (const f16*)(ws + WS_DWHH);
    const float* bias = (const float*)(ws + WS_BIAS);
    const f16* w1f = (const f16*)(ws + WS_W1F);
    const f16* w2f = (const f16*)(ws + WS_W2F);
    const f16* fcwf = (const f16*)(ws + WS_FCWF);

    // ================= CNN prologue (16 images = this block's rows) =================
    {
        const float* imgp = cin + (size_t)(row0 + nl) * 1728 + quad * 8;
        float b1v = b1[nl];
        for (int p = wv; p < 9; p += 8) {
            int oy = p / 3, ox = p % 3;
            f32x4 acc = {b1v, b1v, b1v, b1v};
            #pragma unroll
            for (int kk = 0; kk < 9; kk++) {
                f16x8 bw = *(const f16x8*)(w1f + (kk * 16 + nl) * 32 + quad * 8);
                int pix = (2 * oy + kk / 3) * 8 + (2 * ox + kk % 3);
                const float* s = imgp + pix * 27;
                f16x8 a;
                #pragma unroll
                for (int jj = 0; jj < 8; jj++) a[jj] = (f16)s[jj];
                acc = mfma16(a, bw, acc);
            }
            #pragma unroll
            for (int r = 0; r < 4; r++)
                a1f[quad * 4 + r][p][nl] = (f16)fmaxf(acc[r], 0.0f);
        }
        __syncthreads();
        // conv2: 4 positions x 2 nt = 8 units -> one per wave
        {
            int pos = wv >> 1, nt = wv & 1;
            int y = pos >> 1, x = pos & 1;
            float bv = b2[nt * 16 + nl];
            f32x4 acc = {bv, bv, bv, bv};
            #pragma unroll
            for (int s = 0; s < 2; s++) {
                int kk2 = 2 * s + (quad >> 1);
                int pos1 = (y + (kk2 >> 1)) * 3 + (x + (kk2 & 1));
                f16x8 a = *(const f16x8*)(&a1f[nl][pos1][(quad & 1) * 8]);
                f16x8 b = *(const f16x8*)(w2f + ((size_t)s * 32 + nt * 16 + nl) * 32 + quad * 8);
                acc = mfma16(a, b, acc);
            }
            #pragma unroll
            for (int r = 0; r < 4; r++)
                vf[quad * 4 + r][(nt * 16 + nl) * 4 + (y * 2 + x)] = (f16)fmaxf(acc[r], 0.0f);
        }
        __syncthreads();
        // fc 128->128: wave wv -> outputs wv*16..wv*16+15, straight into pn_s[:, 0..127]
        {
            int o = wv * 16 + nl;
            float bv = fcb[o];
            f32x4 acc = {bv, bv, bv, bv};
            #pragma unroll
            for (int kt = 0; kt < 4; kt++) {
                f16x8 a = *(const f16x8*)(&vf[nl][kt * 32 + quad * 8]);
                f16x8 b = *(const f16x8*)(fcwf + o * 128 + kt * 32 + quad * 8);
                acc = mfma16(a, b, acc);
            }
            #pragma unroll
            for (int r = 0; r < 4; r++)
                pn_s[quad * 4 + r][o] = fmaxf(acc[r], 0.0f);
        }
        __syncthreads();   // a1f dead; safe to zero h_s below
    }

    for (int i = tid; i < 2 * 16 * 136; i += 512) ((f16*)h_s)[i] = (f16)0.0f;

    const int rsw = (nl & 8) ? 16 : 0;    // read-side swizzle (row = nl)
    const int wrow = quad * 4;            // write rows wrow..wrow+3
    const int wsw = (quad >= 2) ? 16 : 0; // write-side swizzle (rows 8-15)
    const int wcol = (j0 + nl + wsw) & 127;
    const int c0 = (quad * 8 + rsw) & 127;
    const int c1 = (32 + quad * 8 + rsw) & 127;
    const int c2 = (64 + quad * 8 + rsw) & 127;
    const int c3 = (96 + quad * 8 + rsw) & 127;

    float ho[4];
    #pragma unroll
    for (int r = 0; r < 4; r++) ho[r] = 0.0f;

    const int xr = tid >> 5, xc = tid & 31;   // x staging: 16 rows x 32 cols
    const bool xok = (xc < 29);
    const size_t lin_base = (size_t)(row0 + xr) * 1856 + xc;

    // ================= encoder =================
    {
        float eb_r, eb_z, eb_xn, eb_hn;
        { int c = j0 + nl;
          eb_r = bias[c]; eb_z = bias[128 + c]; eb_xn = bias[256 + c]; eb_hn = bias[384 + c]; }
        f16x8 we_r[4], we_z[4], we_hn[4], we_xr, we_xz, we_xn;
        { int gr = j0 + nl;
          #pragma unroll
          for (int kt = 0; kt < 4; kt++) {
              we_r[kt]  = *(const f16x8*)(ewhh + gr * 128 + kt * 32 + quad * 8);
              we_z[kt]  = *(const f16x8*)(ewhh + (128 + gr) * 128 + kt * 32 + quad * 8);
              we_hn[kt] = *(const f16x8*)(ewhh + (256 + gr) * 128 + kt * 32 + quad * 8);
          }
          we_xr = *(const f16x8*)(ewih + gr * 32 + quad * 8);
          we_xz = *(const f16x8*)(ewih + (128 + gr) * 32 + quad * 8);
          we_xn = *(const f16x8*)(ewih + (256 + gr) * 32 + quad * 8);
        }

        float xv = xok ? lin[lin_base] : 0.0f;

#define ENC_STEP(BUF, OBUF, TN)                                                      \
        do {                                                                         \
            x_s[BUF][xr][xc] = (f16)xv;                                              \
            __syncthreads();                                                         \
            f16x8 ax = *(const f16x8*)(&x_s[BUF][nl][quad * 8]);                     \
            f16x8 ah0 = *(const f16x8*)(&h_s[BUF][nl][c0]);                          \
            f16x8 ah1 = *(const f16x8*)(&h_s[BUF][nl][c1]);                          \
            f16x8 ah2 = *(const f16x8*)(&h_s[BUF][nl][c2]);                          \
            f16x8 ah3 = *(const f16x8*)(&h_s[BUF][nl][c3]);                          \
            if ((TN) < 64) xv = xok ? lin[lin_base + (TN) * 29] : 0.0f;              \
            f32x4 aR  = {eb_r, eb_r, eb_r, eb_r};                                    \
            f32x4 aZ  = {eb_z, eb_z, eb_z, eb_z};                                    \
            f32x4 aXN = {eb_xn, eb_xn, eb_xn, eb_xn};                                \
            f32x4 aHN = {eb_hn, eb_hn, eb_hn, eb_hn};                                \
            aR  = mfma16(ax, we_xr, aR);                                             \
            aZ  = mfma16(ax, we_xz, aZ);                                             \
            aXN = mfma16(ax, we_xn, aXN);                                            \
            aR  = mfma16(ah0, we_r[0], aR);  aR  = mfma16(ah1, we_r[1], aR);         \
            aR  = mfma16(ah2, we_r[2], aR);  aR  = mfma16(ah3, we_r[3], aR);         \
            aZ  = mfma16(ah0, we_z[0], aZ);  aZ  = mfma16(ah1, we_z[1], aZ);         \
            aZ  = mfma16(ah2, we_z[2], aZ);  aZ  = mfma16(ah3, we_z[3], aZ);         \
            aHN = mfma16(ah0, we_hn[0], aHN); aHN = mfma16(ah1, we_hn[1], aHN);      \
            aHN = mfma16(ah2, we_hn[2], aHN); aHN = mfma16(ah3, we_hn[3], aHN);      \
            _Pragma("unroll")                                                        \
            for (int r = 0; r < 4; r++) {                                            \
                float ea = fexp2n(aR[r]), eb = fexp2n(aZ[r]);                        \
                float s1 = 1.0f + ea, s2 = 1.0f + eb;                                \
                float R = __builtin_amdgcn_rcpf(s1 * s2);                            \
                float rg = s2 * R, zg = s1 * R;                                      \
                float ec = fexp2n(2.0f * (aXN[r] + rg * aHN[r]));                    \
                float ng = (1.0f - ec) * __builtin_amdgcn_rcpf(1.0f + ec);           \
                float h = ng + zg * (ho[r] - ng);                                    \
                ho[r] = h;                                                           \
                h_s[OBUF][wrow + r][wcol] = (f16)h;                                  \
            }                                                                        \
        } while (0)

        for (int t = 0; t < 64; t += 2) {
            ENC_STEP(0, 1, t + 1);
            ENC_STEP(1, 0, t + 2);
        }
#undef ENC_STEP
    }

    // ================= decoder =================
    float db_r, db_z, db_xn, db_hn;
    { int c = j0 + nl;
      db_r = bias[512 + c]; db_z = bias[640 + c]; db_xn = bias[768 + c]; db_hn = bias[896 + c]; }

    // step 0: xin = 0 -> gx = bih; Whh-only frags streamed once (reads h_s[0], writes h_s[1])
    {
        __syncthreads();
        f16x8 ah0 = *(const f16x8*)(&h_s[0][nl][c0]);
        f16x8 ah1 = *(const f16x8*)(&h_s[0][nl][c1]);
        f16x8 ah2 = *(const f16x8*)(&h_s[0][nl][c2]);
        f16x8 ah3 = *(const f16x8*)(&h_s[0][nl][c3]);
        int gr = j0 + nl;
        f32x4 aR  = {db_r, db_r, db_r, db_r};
        f32x4 aZ  = {db_z, db_z, db_z, db_z};
        f32x4 aHN = {db_hn, db_hn, db_hn, db_hn};
        #pragma unroll
        for (int kt = 0; kt < 4; kt++) {
            f16x8 b0 = *(const f16x8*)(dwhh + gr * 128 + kt * 32 + quad * 8);
            f16x8 b1 = *(const f16x8*)(dwhh + (128 + gr) * 128 + kt * 32 + quad * 8);
            f16x8 b2 = *(const f16x8*)(dwhh + (256 + gr) * 128 + kt * 32 + quad * 8);
            f16x8 a = (kt == 0) ? ah0 : (kt == 1) ? ah1 : (kt == 2) ? ah2 : ah3;
            aR  = mfma16(a, b0, aR);
            aZ  = mfma16(a, b1, aZ);
            aHN = mfma16(a, b2, aHN);
        }
        #pragma unroll
        for (int r = 0; r < 4; r++) {
            float ea = fexp2n(aR[r]), eb = fexp2n(aZ[r]);
            float s1 = 1.0f + ea, s2 = 1.0f + eb;
            float R = __builtin_amdgcn_rcpf(s1 * s2);
            float rg = s2 * R, zg = s1 * R;
            float ec = fexp2n(2.0f * (db_xn + rg * aHN[r]));
            float ng = (1.0f - ec) * __builtin_amdgcn_rcpf(1.0f + ec);
            float h = ng + zg * (ho[r] - ng);
            ho[r] = h;
            h_s[1][wrow + r][wcol] = (f16)h;
        }
    }
    // steps 1..63: xin == h -> combined weights
    {
        f16x8 wd_r[4], wd_z[4], wd_xn[4], wd_hn[4];
        { int gr = j0 + nl;
          #pragma unroll
          for (int kt = 0; kt < 4; kt++) {
              wd_r[kt]  = *(const f16x8*)(dwc + gr * 128 + kt * 32 + quad * 8);
              wd_z[kt]  = *(const f16x8*)(dwc + (128 + gr) * 128 + kt * 32 + quad * 8);
              wd_xn[kt] = *(const f16x8*)(dwc + (256 + gr) * 128 + kt * 32 + quad * 8);
              wd_hn[kt] = *(const f16x8*)(dwc + (384 + gr) * 128 + kt * 32 + quad * 8);
          }
        }

#define DEC_STEP(BUF, OBUF)                                                          \
        do {                                                                         \
            __syncthreads();                                                         \
            f16x8 ah0 = *(const f16x8*)(&h_s[BUF][nl][c0]);                          \
            f16x8 ah1 = *(const f16x8*)(&h_s[BUF][nl][c1]);                          \
            f16x8 ah2 = *(const f16x8*)(&h_s[BUF][nl][c2]);                          \
            f16x8 ah3 = *(const f16x8*)(&h_s[BUF][nl][c3]);                          \
            f32x4 aR  = {db_r, db_r, db_r, db_r};                                    \
            f32x4 aZ  = {db_z, db_z, db_z, db_z};                                    \
            f32x4 aXN = {db_xn, db_xn, db_xn, db_xn};                                \
            f32x4 aHN = {db_hn, db_hn, db_hn, db_hn};                                \
            aR  = mfma16(ah0, wd_r[0], aR);   aR  = mfma16(ah1, wd_r[1], aR);        \
            aR  = mfma16(ah2, wd_r[2], aR);   aR  = mfma16(ah3, wd_r[3], aR);        \
            aZ  = mfma16(ah0, wd_z[0], aZ);   aZ  = mfma16(ah1, wd_z[1], aZ);        \
            aZ  = mfma16(ah2, wd_z[2], aZ);   aZ  = mfma16(ah3, wd_z[3], aZ);        \
            aXN = mfma16(ah0, wd_xn[0], aXN); aXN = mfma16(ah1, wd_xn[1], aXN);      \
            aXN = mfma16(ah2, wd_xn[2], aXN); aXN = mfma16(ah3, wd_xn[3], aXN);      \
            aHN = mfma16(ah0, wd_hn[0], aHN); aHN = mfma16(ah1, wd_hn[1], aHN);      \
            aHN = mfma16(ah2, wd_hn[2], aHN); aHN = mfma16(ah3, wd_hn[3], aHN);      \
            _Pragma("unroll")                                                        \
            for (int r = 0; r < 4; r++) {                                            \
                float ea = fexp2n(aR[r]), eb = fexp2n(aZ[r]);                        \
                float s1 = 1.0f + ea, s2 = 1.0f + eb;                                \
                float R = __builtin_amdgcn_rcpf(s1 * s2);                            \
                float rg = s2 * R, zg = s1 * R;                                      \
                float ec = fexp2n(2.0f * (aXN[r] + rg * aHN[r]));                    \
                float ng = (1.0f - ec) * __builtin_amdgcn_rcpf(1.0f + ec);           \
                float h = ng + zg * (ho[r] - ng);                                    \
                ho[r] = h;                                                           \
                h_s[OBUF][wrow + r][wcol] = (f16)h;                                  \
            }                                                                        \
        } while (0)

        DEC_STEP(1, 0);            // step 1
        for (int t = 2; t < 64; t += 2) {
            DEC_STEP(0, 1);
            DEC_STEP(1, 0);
        }
#undef DEC_STEP
    }

    // ================= heads (pn_s cols 0..127 already hold z_cnn) =================
    #pragma unroll
    for (int r = 0; r < 4; r++)
        pn_s[wrow + r][128 + j0 + nl] = ho[r];
    __syncthreads();

    const int rr = tid & 15, og = tid >> 4;   // og 0..31
    const float4* pr4 = (const float4*)(&pn_s[rr][0]);
    for (int o = og; o < 79; o += 32) {
        const float* wrow_p = (o < 78) ? (dis_w + o * 256) : value_w;
        float acc = (o < 78) ? dis_b[o] : value_b[0];
        const float4* wr4 = (const float4*)wrow_p;
        #pragma unroll 8
        for (int k = 0; k < 64; k++) {
            float4 a = wr4[k], b = pr4[k];
            acc += a.x * b.x + a.y * b.y + a.z * b.z + a.w * b.w;
        }
        if (o < 78) out[(size_t)(row0 + rr) * 78 + o] = acc;
        else        out[(size_t)8192 * 78 + row0 + rr] = acc;
    }
}

extern "C" void kernel_launch(void* const* d_in, const int* in_sizes, int n_in,
                              void* d_out, int out_size, void* d_ws, size_t ws_size,
                              hipStream_t stream)
{
    (void)in_sizes; (void)n_in; (void)out_size; (void)ws_size;
    const float* cnn  = (const float*)d_in[0];
    const float* lin  = (const float*)d_in[1];
    const float* c1w  = (const float*)d_in[2];
    const float* c1b  = (const float*)d_in[3];
    const float* c2w  = (const float*)d_in[4];
    const float* c2b  = (const float*)d_in[5];
    const float* fcw  = (const float*)d_in[6];
    const float* fcb  = (const float*)d_in[7];
    const float* eWih = (const float*)d_in[8];
    const float* eWhh = (const float*)d_in[9];
    const float* ebih = (const float*)d_in[10];
    const float* ebhh = (const float*)d_in[11];
    const float* dWih = (const float*)d_in[12];
    const float* dWhh = (const float*)d_in[13];
    const float* dbih = (const float*)d_in[14];
    const float* dbhh = (const float*)d_in[15];
    const float* disw = (const float*)d_in[16];
    const float* disb = (const float*)d_in[17];
    const float* vw   = (const float*)d_in[18];
    const float* vb   = (const float*)d_in[19];
    char* ws = (char*)d_ws;
    float* out = (float*)d_out;

    hipLaunchKernelGGL(k_prep, dim3(128), dim3(256), 0, stream,
                       eWih, eWhh, ebih, ebhh, dWih, dWhh, dbih, dbhh,
                       c1w, c2w, fcw, ws);
    hipLaunchKernelGGL(k_gru, dim3(512), dim3(512), 0, stream,
                       cnn, lin, c1b, c2b, fcb, ws, disw, disb, vw, vb, out);
}